// Round 10
// baseline (461.908 us; speedup 1.0000x reference)
//
#include <hip/hip_runtime.h>
#include <hip/hip_fp16.h>
#include <cstdint>
#include <cstddef>

#define NN 100000
#define NROWS 100032               // NN rounded up to 64 (GEMM tile padding)
#define NE 1600000
#define NEP (NE + NN)              // 1,700,000
#define NBLK 200                   // partition blocks
#define CHUNK ((NEP + NBLK - 1) / NBLK)   // 8500
#define NBUCK2 ((NN + 255) / 256)  // 391 buckets of 256 dst nodes
#define HISTN (NBUCK2 * NBLK)      // 78,200
#define HSCAN_BLOCKS ((HISTN + 1023) / 1024)  // 77
#define NT64 ((NN + 63) / 64)      // 1563 row tiles

typedef __attribute__((ext_vector_type(8))) _Float16 half8;
typedef __attribute__((ext_vector_type(2))) _Float16 h2v;
typedef __attribute__((ext_vector_type(4))) float float4v;

__device__ __forceinline__ float elu_f(float x) {
    return x > 0.f ? x : __expf(x) - 1.f;
}

// ---- DPP reduce helpers ----
template<int CTRL>
__device__ __forceinline__ float dpp_add(float x) {
    int s = __builtin_amdgcn_update_dpp(0, __float_as_int(x), CTRL, 0xF, 0xF, true);
    return x + __int_as_float(s);
}
// sum over aligned lane PAIRS (gat1 head = 2 lanes x 16ch)
__device__ __forceinline__ float sum2_all(float x) { return dpp_add<0xB1>(x); }
// sum over aligned QUADS (gat2 edge = 4 lanes x 8ch)
__device__ __forceinline__ float sum4_all(float x) {
    x = dpp_add<0xB1>(x); x = dpp_add<0x4E>(x);
    return x;
}

__device__ __forceinline__ float dot2f(h2v a, h2v b, float c) {
#if __has_builtin(__builtin_amdgcn_fdot2)
    return __builtin_amdgcn_fdot2(a, b, c, false);
#else
    return fmaf((float)a[0], (float)b[0], fmaf((float)a[1], (float)b[1], c));
#endif
}

__device__ __forceinline__ h2v hmax2v(h2v a, h2v b) {
#if __has_builtin(__builtin_elementwise_max)
    return __builtin_elementwise_max(a, b);
#else
    __half2 r = __hmax2(*(__half2*)&a, *(__half2*)&b);
    return *(h2v*)&r;
#endif
}

// ================= CSR build: deterministic radix partition =================

__global__ __launch_bounds__(256) void part_hist(const int* __restrict__ ei, int* __restrict__ hist)
{
    __shared__ int cnt[NBUCK2];
    int tid = threadIdx.x, k = blockIdx.x;
    for (int i = tid; i < NBUCK2; i += 256) cnt[i] = 0;
    __syncthreads();
    int e0 = k * CHUNK, e1 = min(e0 + CHUNK, NEP);
    for (int e = e0 + tid; e < e1; e += 256) {
        int dst = (e < NE) ? ei[NE + e] : e - NE;
        atomicAdd(&cnt[dst >> 8], 1);
    }
    __syncthreads();
    for (int i = tid; i < NBUCK2; i += 256) hist[i * NBLK + k] = cnt[i];
}

__global__ __launch_bounds__(256) void scan_p1(const int* __restrict__ src, int* __restrict__ part, int n)
{
    __shared__ int wsum[4];
    int t = threadIdx.x;
    int i0 = blockIdx.x * 1024 + t * 4;
    int s = 0;
    if (i0 + 3 < n) { int4 d = *(const int4*)(src + i0); s = d.x + d.y + d.z + d.w; }
    else { for (int k = 0; k < 4; k++) if (i0 + k < n) s += src[i0 + k]; }
    for (int d = 1; d < 64; d <<= 1) s += __shfl_xor(s, d, 64);
    if ((t & 63) == 0) wsum[t >> 6] = s;
    __syncthreads();
    if (t == 0) part[blockIdx.x] = wsum[0] + wsum[1] + wsum[2] + wsum[3];
}

__global__ __launch_bounds__(128) void scan_p2(int* __restrict__ part, int nb, int* __restrict__ off)
{
    __shared__ int wt[2];
    int t = threadIdx.x;
    int lane = t & 63, w = t >> 6;
    int v = (t < nb) ? part[t] : 0;
    int x = v;
    for (int d = 1; d < 64; d <<= 1) { int y = __shfl_up(x, d, 64); if (lane >= d) x += y; }
    if (lane == 63) wt[w] = x;
    __syncthreads();
    int base = (w == 1) ? wt[0] : 0;
    int excl = base + x - v;
    if (t < nb) part[t] = excl;
    if (t == 0) off[NN] = NEP;
}

__global__ __launch_bounds__(256) void scan_p3(int* __restrict__ data, const int* __restrict__ part, int n)
{
    __shared__ int wsum[4];
    int t = threadIdx.x, lane = t & 63, w = t >> 6;
    int i0 = blockIdx.x * 1024 + t * 4;
    int d0 = 0, d1 = 0, d2 = 0, d3 = 0;
    if (i0 + 3 < n) { int4 d = *(const int4*)(data + i0); d0 = d.x; d1 = d.y; d2 = d.z; d3 = d.w; }
    else if (i0 < n) {
        d0 = data[i0];
        if (i0 + 1 < n) d1 = data[i0 + 1];
        if (i0 + 2 < n) d2 = data[i0 + 2];
    }
    int s = d0 + d1 + d2 + d3;
    int x = s;
    for (int d = 1; d < 64; d <<= 1) { int y = __shfl_up(x, d, 64); if (lane >= d) x += y; }
    if (lane == 63) wsum[w] = x;
    __syncthreads();
    int wb = 0;
    for (int i = 0; i < w; i++) wb += wsum[i];
    int base = part[blockIdx.x] + wb + x - s;
    if (i0 < n)     data[i0]     = base;
    if (i0 + 1 < n) data[i0 + 1] = base + d0;
    if (i0 + 2 < n) data[i0 + 2] = base + d0 + d1;
    if (i0 + 3 < n) data[i0 + 3] = base + d0 + d1 + d2;
}

__global__ __launch_bounds__(256) void part_scatter(const int* __restrict__ ei,
                                                    const int* __restrict__ hist,
                                                    unsigned* __restrict__ ebuf)
{
    __shared__ int cur[NBUCK2];
    int tid = threadIdx.x, k = blockIdx.x;
    for (int i = tid; i < NBUCK2; i += 256) cur[i] = hist[i * NBLK + k];
    __syncthreads();
    int e0 = k * CHUNK, e1 = min(e0 + CHUNK, NEP);
    for (int e = e0 + tid; e < e1; e += 256) {
        int src, dst;
        if (e < NE) { src = ei[e]; dst = ei[NE + e]; } else { src = dst = e - NE; }
        int pos = atomicAdd(&cur[dst >> 8], 1);
        ebuf[pos] = (unsigned)src | ((unsigned)(dst & 255) << 24);
    }
}

__global__ __launch_bounds__(256) void bucket_csr(const int* __restrict__ hist,
                                                  const unsigned* __restrict__ ebuf,
                                                  int* __restrict__ off, int* __restrict__ csr)
{
    __shared__ int cnt[256];
    __shared__ int cur[256];
    __shared__ int wsum[4];
    int b = blockIdx.x;
    int d0 = b << 8;
    int tid = threadIdx.x;
    int e0 = hist[b * NBLK];
    int e1 = (b + 1 < NBUCK2) ? hist[(b + 1) * NBLK] : NEP;
    cnt[tid] = 0;
    __syncthreads();
    for (int i = e0 + tid; i < e1; i += 256) atomicAdd(&cnt[ebuf[i] >> 24], 1);
    __syncthreads();
    int c = cnt[tid];
    int x = c;
    int lane = tid & 63, w = tid >> 6;
    for (int d = 1; d < 64; d <<= 1) { int y = __shfl_up(x, d, 64); if (lane >= d) x += y; }
    if (lane == 63) wsum[w] = x;
    __syncthreads();
    int wb = 0;
    for (int i = 0; i < w; i++) wb += wsum[i];
    int excl = wb + x - c;
    cur[tid] = e0 + excl;
    int node = d0 + tid;
    if (node < NN) off[node] = e0 + excl;
    __syncthreads();
    for (int i = e0 + tid; i < e1; i += 256) {
        unsigned v = ebuf[i];
        int p = atomicAdd(&cur[v >> 24], 1);
        csr[p] = (int)(v & 0xFFFFFF);
    }
}

// ================= node feature prep (fp16 x [N][96]; bio + pca + pad fused) =================

__global__ __launch_bounds__(256) void bio_kernel(
    const float* __restrict__ xb, const float* __restrict__ xp,
    const float* __restrict__ W1, const float* __restrict__ b1,
    const float* __restrict__ g0, const float* __restrict__ bb0,
    const float* __restrict__ m0, const float* __restrict__ v0,
    const float* __restrict__ W2, const float* __restrict__ b2,
    __half* __restrict__ xh)
{
    __shared__ float sW1[16*64], sW2[16*16], sb1[16], sb2[16], ss[16], st[16];
    int tid = threadIdx.x;
    for (int idx = tid; idx < 1024; idx += 256) sW1[idx] = W1[idx];
    if (tid < 256) sW2[tid] = W2[tid];
    if (tid < 16) {
        sb1[tid] = b1[tid]; sb2[tid] = b2[tid];
        float s = g0[tid] * rsqrtf(v0[tid] + 1e-5f);
        ss[tid] = s; st[tid] = bb0[tid] - m0[tid] * s;
    }
    __syncthreads();
    int i = blockIdx.x * 256 + tid;
    if (i >= NN) return;
    float bio[64];
    const float4* p = (const float4*)(xb + (size_t)i * 64);
    #pragma unroll
    for (int q = 0; q < 16; q++) {
        float4 f = p[q];
        bio[q*4] = f.x; bio[q*4+1] = f.y; bio[q*4+2] = f.z; bio[q*4+3] = f.w;
    }
    float t1[16];
    #pragma unroll
    for (int j = 0; j < 16; j++) {
        float acc = sb1[j];
        #pragma unroll
        for (int k = 0; k < 64; k++) acc += bio[k] * sW1[j*64 + k];
        acc = acc * ss[j] + st[j];
        t1[j] = elu_f(acc);
    }
    __half* xrow = xh + (size_t)i * 96;
    const float* xpr = xp + (size_t)i * 50;
    #pragma unroll
    for (int j = 0; j < 25; j++) {
        float2 f = *(const float2*)(xpr + 2 * j);
        *(__half2*)(xrow + 2 * j) = __floats2half2_rn(f.x, f.y);
    }
    #pragma unroll
    for (int j = 0; j < 16; j++) {
        float acc = sb2[j];
        #pragma unroll
        for (int k = 0; k < 16; k++) acc += t1[k] * sW2[j*16 + k];
        xrow[50 + j] = __float2half(elu_f(acc));
    }
    __half2 z2 = __floats2half2_rn(0.f, 0.f);
    #pragma unroll
    for (int j = 0; j < 15; j++) *(__half2*)(xrow + 66 + 2 * j) = z2;
}

// ================= all weight conversions in one launch =================

__global__ __launch_bounds__(256) void wconvert_all(
    const float* __restrict__ Wl1, const float* __restrict__ Wr1,
    const float* __restrict__ bl1, const float* __restrict__ br1,
    const float* __restrict__ Wl2, const float* __restrict__ Wr2,
    const float* __restrict__ bl2, const float* __restrict__ br2,
    const float* __restrict__ predW, const float* __restrict__ predb,
    __half* __restrict__ wcat1, float* __restrict__ bcat1,
    __half* __restrict__ wcat2, float* __restrict__ bcat2,
    __half* __restrict__ wpred, float* __restrict__ bpred)
{
    int t = blockIdx.x * 256 + threadIdx.x;
    if (t < 256 * 96) {
        int j = t / 96, k = t - j * 96;
        float v = (k < 66) ? ((j < 128) ? Wl1[j * 66 + k] : Wr1[(j - 128) * 66 + k]) : 0.f;
        wcat1[t] = __float2half(v);
    }
    int u = t - 256 * 96;
    if (u >= 0 && u < 64 * 128) {
        int j = u >> 7, k = u & 127;
        float v = (j < 32) ? Wl2[j * 128 + k] : Wr2[(j - 32) * 128 + k];
        wcat2[u] = __float2half(v);
    }
    int w = u - 64 * 128;
    if (w >= 0 && w < 64 * 32) {
        int j = w >> 5;
        wpred[w] = __float2half(j < 50 ? predW[w] : 0.f);
    }
    int z = w - 64 * 32;
    if (z >= 0 && z < 256) bcat1[z] = (z < 128) ? bl1[z] : br1[z - 128];
    int z2 = z - 256;
    if (z2 >= 0 && z2 < 64) bcat2[z2] = (z2 < 32) ? bl2[z2] : br2[z2 - 32];
    int z3 = z2 - 64;
    if (z3 >= 0 && z3 < 64) bpred[z3] = (z3 < 50) ? predb[z3] : 0.f;
}

// ================= MFMA f16 GEMM: persistent-W, direct global A =================
// out[n][NC] = in[n][K] @ wcat[NC][K]^T + bcat.  K = KT*32.  4 waves/block,
// 64 rows/tile, grid-stride over tiles; W staged in LDS once per block,
// A-frags loaded straight from global (rows padded to NROWS).
template<int KT, int NC, bool FOUT>
__global__ __launch_bounds__(256) void mfma_gemm(
    const __half* __restrict__ in, const __half* __restrict__ wcat,
    const float* __restrict__ bcat, void* __restrict__ outv, int n, int ncol, int ntiles)
{
    constexpr int K = KT * 32;
    constexpr int KP = K + 8;
    __shared__ __half sW[NC * KP];
    __shared__ float sB[NC];
    int tid = threadIdx.x;
    for (int idx = tid * 8; idx < NC * K; idx += 256 * 8) {
        int r = idx / K, c = idx - r * K;
        *(half8*)(&sW[r * KP + c]) = *(const half8*)(&wcat[r * K + c]);
    }
    for (int idx = tid; idx < NC; idx += 256) sB[idx] = bcat[idx];
    __syncthreads();
    int w = tid >> 6, lane = tid & 63;
    int m = lane & 15, quad = lane >> 4;
    for (int tile = blockIdx.x; tile < ntiles; tile += gridDim.x) {
        int arow = tile * 64 + w * 16 + m;          // < NROWS (padded)
        const __half* inr = in + (size_t)arow * K + quad * 8;
        half8 a[KT];
        #pragma unroll
        for (int kt = 0; kt < KT; kt++) a[kt] = *(const half8*)(inr + kt * 32);
        #pragma unroll 1
        for (int nt = 0; nt < NC / 16; nt++) {
            float4v acc = {0.f, 0.f, 0.f, 0.f};
            #pragma unroll
            for (int kt = 0; kt < KT; kt++) {
                half8 bfrag = *(const half8*)(&sW[(nt * 16 + m) * KP + kt * 32 + quad * 8]);
                acc = __builtin_amdgcn_mfma_f32_16x16x32_f16(a[kt], bfrag, acc, 0, 0, 0);
            }
            int col = nt * 16 + m;
            float bias = sB[col];
            #pragma unroll
            for (int i = 0; i < 4; i++) {
                int r = tile * 64 + w * 16 + quad * 4 + i;
                if (r < n) {
                    if (FOUT) { if (col < ncol) ((float*)outv)[(size_t)r * ncol + col] = acc[i] + bias; }
                    else ((__half*)outv)[(size_t)r * NC + col] = __float2half(acc[i] + bias);
                }
            }
        }
    }
}

// ================= fused GATv2 layer 1: 8 edges/iter x 8 lanes x 16ch =================
// xcat [N][256] fp16 (xl 0..127, xr 128..255). row=lane>>3 edge slot, cl=lane&7,
// ch=16*cl. Head = 32 ch = 2 lanes -> sum2_all (1 DPP).
__global__ __launch_bounds__(256) void fused_gat1(
    const int* __restrict__ off, const int* __restrict__ csr,
    const __half* __restrict__ xcat, const float* __restrict__ att,
    const float* __restrict__ bias, const float* __restrict__ g,
    const float* __restrict__ b, const float* __restrict__ m,
    const float* __restrict__ v, __half* __restrict__ h1)
{
    int wave = threadIdx.x >> 6;
    int lane = threadIdx.x & 63;
    int node = blockIdx.x * 4 + wave;
    if (node >= NN) return;
    int row = lane >> 3;       // edge slot 0..7
    int cl  = lane & 7;
    int ch  = cl * 16;

    half8 xrA = *(const half8*)(xcat + (size_t)node * 256 + 128 + ch);
    half8 xrB = *(const half8*)(xcat + (size_t)node * 256 + 128 + ch + 8);
    h2v ath[8];
    #pragma unroll
    for (int q = 0; q < 4; q++) {
        float4 af = *(const float4*)(att + ch + 4 * q);
        ath[2*q]   = h2v{(_Float16)af.x, (_Float16)af.y};
        ath[2*q+1] = h2v{(_Float16)af.z, (_Float16)af.w};
    }
    const h2v c2 = {(_Float16)0.2f, (_Float16)0.2f};

    int k0 = off[node], k1 = off[node + 1];
    float acc[16];
    #pragma unroll
    for (int i = 0; i < 16; i++) acc[i] = 0.f;
    float denom = 0.f;

    for (int base = k0; base < k1; base += 64) {
        int nb = min(64, k1 - base);
        int mysrc = (lane < nb) ? csr[base + lane] : 0;
        int nbm1 = nb - 1;
        int ss = __shfl(mysrc, min(row, nbm1), 64);
        const __half* xrow0 = xcat + (size_t)(unsigned)ss * 256 + ch;
        half8 curA = *(const half8*)xrow0;
        half8 curB = *(const half8*)(xrow0 + 8);
        for (int t = 0; t < nb; t += 8) {
            int ns = __shfl(mysrc, min(t + 8 + row, nbm1), 64);
            const __half* xrown = xcat + (size_t)(unsigned)ns * 256 + ch;
            half8 nxtA = *(const half8*)xrown;
            half8 nxtB = *(const half8*)(xrown + 8);

            float pp = 0.f;
            #pragma unroll
            for (int i = 0; i < 4; i++) {
                h2v xl = {curA[2*i], curA[2*i+1]};
                h2v xr = {xrA[2*i], xrA[2*i+1]};
                h2v s = xl + xr;
                h2v l = hmax2v(s, s * c2);
                pp = dot2f(l, ath[i], pp);
            }
            #pragma unroll
            for (int i = 0; i < 4; i++) {
                h2v xl = {curB[2*i], curB[2*i+1]};
                h2v xr = {xrB[2*i], xrB[2*i+1]};
                h2v s = xl + xr;
                h2v l = hmax2v(s, s * c2);
                pp = dot2f(l, ath[4+i], pp);
            }
            pp = sum2_all(pp);                 // per-head (lane-pair) logit
            bool valid = (t + row) < nb;
            float wgt = valid ? __expf(pp) : 0.f;
            denom += wgt;
            #pragma unroll
            for (int i = 0; i < 8; i++) acc[i] = fmaf((float)curA[i], wgt, acc[i]);
            #pragma unroll
            for (int i = 0; i < 8; i++) acc[8+i] = fmaf((float)curB[i], wgt, acc[8+i]);
            curA = nxtA; curB = nxtB;
        }
    }
    // combine 8 edge slots (lane bits 3,4,5)
    #pragma unroll
    for (int i = 0; i < 16; i++) {
        acc[i] += __shfl_xor(acc[i], 8, 64);
        acc[i] += __shfl_xor(acc[i], 16, 64);
        acc[i] += __shfl_xor(acc[i], 32, 64);
    }
    denom += __shfl_xor(denom, 8, 64);
    denom += __shfl_xor(denom, 16, 64);
    denom += __shfl_xor(denom, 32, 64);
    if (row == 0) {
        float inv = 1.f / (denom + 1e-16f);
        _Float16 oh[16];
        #pragma unroll
        for (int q = 0; q < 4; q++) {
            float4 gv = *(const float4*)(g + ch + 4*q);
            float4 vv = *(const float4*)(v + ch + 4*q);
            float4 bv = *(const float4*)(b + ch + 4*q);
            float4 mv = *(const float4*)(m + ch + 4*q);
            float4 iv = *(const float4*)(bias + ch + 4*q);
            float sc;
            sc = gv.x * rsqrtf(vv.x + 1e-5f); oh[4*q+0] = (_Float16)elu_f((acc[4*q+0] * inv + iv.x) * sc + (bv.x - mv.x * sc));
            sc = gv.y * rsqrtf(vv.y + 1e-5f); oh[4*q+1] = (_Float16)elu_f((acc[4*q+1] * inv + iv.y) * sc + (bv.y - mv.y * sc));
            sc = gv.z * rsqrtf(vv.z + 1e-5f); oh[4*q+2] = (_Float16)elu_f((acc[4*q+2] * inv + iv.z) * sc + (bv.z - mv.z * sc));
            sc = gv.w * rsqrtf(vv.w + 1e-5f); oh[4*q+3] = (_Float16)elu_f((acc[4*q+3] * inv + iv.w) * sc + (bv.w - mv.w * sc));
        }
        half8 oA = {oh[0], oh[1], oh[2], oh[3], oh[4], oh[5], oh[6], oh[7]};
        half8 oB = {oh[8], oh[9], oh[10], oh[11], oh[12], oh[13], oh[14], oh[15]};
        *(half8*)(h1 + (size_t)node * 128 + ch) = oA;
        *(half8*)(h1 + (size_t)node * 128 + ch + 8) = oB;
    }
}

// ================= fused GATv2 layer 2: 16 edges/iter x 4 lanes x 8ch =================
// xcat2 [N][64] fp16 (xl 0..31, xr 32..63). row=lane>>2 edge slot, cl=lane&3, ch=8*cl.
__global__ __launch_bounds__(256) void fused_gat2(
    const int* __restrict__ off, const int* __restrict__ csr,
    const __half* __restrict__ xcat2, const float* __restrict__ att,
    const float* __restrict__ bias, const float* __restrict__ g,
    const float* __restrict__ b, const float* __restrict__ m,
    const float* __restrict__ v, __half* __restrict__ h2)
{
    int wave = threadIdx.x >> 6;
    int lane = threadIdx.x & 63;
    int node = blockIdx.x * 4 + wave;
    if (node >= NN) return;
    int row = lane >> 2;       // edge slot 0..15
    int cl  = lane & 3;
    int ch  = cl * 8;

    half8 xr8 = *(const half8*)(xcat2 + (size_t)node * 64 + 32 + ch);
    h2v ath[4];
    #pragma unroll
    for (int q = 0; q < 2; q++) {
        float4 af = *(const float4*)(att + ch + 4 * q);
        ath[2*q]   = h2v{(_Float16)af.x, (_Float16)af.y};
        ath[2*q+1] = h2v{(_Float16)af.z, (_Float16)af.w};
    }
    const h2v c2 = {(_Float16)0.2f, (_Float16)0.2f};

    int k0 = off[node], k1 = off[node + 1];
    float acc[8];
    #pragma unroll
    for (int i = 0; i < 8; i++) acc[i] = 0.f;
    float denom = 0.f;

    for (int base = k0; base < k1; base += 64) {
        int nb = min(64, k1 - base);
        int mysrc = (lane < nb) ? csr[base + lane] : 0;
        int nbm1 = nb - 1;
        int ss = __shfl(mysrc, min(row, nbm1), 64);
        half8 cur = *(const half8*)(xcat2 + (size_t)(unsigned)ss * 64 + ch);
        for (int t = 0; t < nb; t += 16) {
            int ns = __shfl(mysrc, min(t + 16 + row, nbm1), 64);
            half8 nxt = *(const half8*)(xcat2 + (size_t)(unsigned)ns * 64 + ch);

            float pp = 0.f;
            #pragma unroll
            for (int i = 0; i < 4; i++) {
                h2v xl = {cur[2*i], cur[2*i+1]};
                h2v xr = {xr8[2*i], xr8[2*i+1]};
                h2v s = xl + xr;
                h2v l = hmax2v(s, s * c2);
                pp = dot2f(l, ath[i], pp);
            }
            pp = sum4_all(pp);                 // per-edge (quad) 32-ch logit
            bool valid = (t + row) < nb;
            float wgt = valid ? __expf(pp) : 0.f;
            denom += wgt;
            #pragma unroll
            for (int i = 0; i < 8; i++) acc[i] = fmaf((float)cur[i], wgt, acc[i]);
            cur = nxt;
        }
    }
    // combine 16 edge slots (lane bits 2..5)
    #pragma unroll
    for (int i = 0; i < 8; i++) {
        acc[i] += __shfl_xor(acc[i], 4, 64);
        acc[i] += __shfl_xor(acc[i], 8, 64);
        acc[i] += __shfl_xor(acc[i], 16, 64);
        acc[i] += __shfl_xor(acc[i], 32, 64);
    }
    denom += __shfl_xor(denom, 4, 64);
    denom += __shfl_xor(denom, 8, 64);
    denom += __shfl_xor(denom, 16, 64);
    denom += __shfl_xor(denom, 32, 64);
    if (row == 0) {
        float inv = 1.f / (denom + 1e-16f);
        _Float16 oh[8];
        #pragma unroll
        for (int q = 0; q < 2; q++) {
            float4 gv = *(const float4*)(g + ch + 4*q);
            float4 vv = *(const float4*)(v + ch + 4*q);
            float4 bv = *(const float4*)(b + ch + 4*q);
            float4 mv = *(const float4*)(m + ch + 4*q);
            float4 iv = *(const float4*)(bias + ch + 4*q);
            float sc;
            sc = gv.x * rsqrtf(vv.x + 1e-5f); oh[4*q+0] = (_Float16)elu_f((acc[4*q+0] * inv + iv.x) * sc + (bv.x - mv.x * sc));
            sc = gv.y * rsqrtf(vv.y + 1e-5f); oh[4*q+1] = (_Float16)elu_f((acc[4*q+1] * inv + iv.y) * sc + (bv.y - mv.y * sc));
            sc = gv.z * rsqrtf(vv.z + 1e-5f); oh[4*q+2] = (_Float16)elu_f((acc[4*q+2] * inv + iv.z) * sc + (bv.z - mv.z * sc));
            sc = gv.w * rsqrtf(vv.w + 1e-5f); oh[4*q+3] = (_Float16)elu_f((acc[4*q+3] * inv + iv.w) * sc + (bv.w - mv.w * sc));
        }
        half8 o = {oh[0], oh[1], oh[2], oh[3], oh[4], oh[5], oh[6], oh[7]};
        *(half8*)(h2 + (size_t)node * 32 + ch) = o;
    }
}

extern "C" void kernel_launch(void* const* d_in, const int* in_sizes, int n_in,
                              void* d_out, int out_size, void* d_ws, size_t ws_size,
                              hipStream_t stream)
{
    const float* x_pca = (const float*)d_in[0];
    const float* x_bio = (const float*)d_in[1];
    const int*   ei    = (const int*)d_in[2];
    const float* bioW1 = (const float*)d_in[3];
    const float* biob1 = (const float*)d_in[4];
    const float* bn0_g = (const float*)d_in[5];
    const float* bn0_b = (const float*)d_in[6];
    const float* bn0_m = (const float*)d_in[7];
    const float* bn0_v = (const float*)d_in[8];
    const float* bioW2 = (const float*)d_in[9];
    const float* biob2 = (const float*)d_in[10];
    const float* Wl1   = (const float*)d_in[11];
    const float* bl1   = (const float*)d_in[12];
    const float* Wr1   = (const float*)d_in[13];
    const float* br1   = (const float*)d_in[14];
    const float* att1  = (const float*)d_in[15];
    const float* bias1 = (const float*)d_in[16];
    const float* bn1_g = (const float*)d_in[17];
    const float* bn1_b = (const float*)d_in[18];
    const float* bn1_m = (const float*)d_in[19];
    const float* bn1_v = (const float*)d_in[20];
    const float* Wl2   = (const float*)d_in[21];
    const float* bl2   = (const float*)d_in[22];
    const float* Wr2   = (const float*)d_in[23];
    const float* br2   = (const float*)d_in[24];
    const float* att2  = (const float*)d_in[25];
    const float* bias2 = (const float*)d_in[26];
    const float* bn2_g = (const float*)d_in[27];
    const float* bn2_b = (const float*)d_in[28];
    const float* bn2_m = (const float*)d_in[29];
    const float* bn2_v = (const float*)d_in[30];
    const float* predW = (const float*)d_in[31];
    const float* predb = (const float*)d_in[32];

    float* ws = (float*)d_ws;
    __half* xh    = (__half*)ws;                       // NROWS*96 h = 4,801,536 f
    float*  p0    = ws + 4801536;
    __half* xcat1 = (__half*)p0;                       // NROWS*256 h = 12,804,096 f
    float*  p1    = p0 + 12804096;
    __half* h1h   = (__half*)p1;                       // NROWS*128 h = 6,402,048 f
    float*  p2    = p1 + 6402048;
    __half* xcat2 = (__half*)p2;                       // NROWS*64 h = 3,201,024 f
    float*  p3    = p2 + 3201024;
    __half* h2h   = (__half*)p3;                       // NROWS*32 h = 1,600,512 f
    float*  p4    = p3 + 1600512;
    __half* wcat1 = (__half*)p4;                       // 256*96 h
    float*  bcat1 = p4 + 12288;                        // 256
    __half* wcat2 = (__half*)(bcat1 + 256);            // 64*128 h
    float*  bcat2 = bcat1 + 256 + 4096;                // 64
    __half* wpred = (__half*)(bcat2 + 64);             // 64*32 h
    float*  bpred = bcat2 + 64 + 1024;                 // 64
    int*    ib    = (int*)(bpred + 64);
    unsigned* ebuf = (unsigned*)ib;                    // NEP
    int*    hist   = ib + NEP;                         // HISTN
    int*    part   = hist + HISTN;                     // 128
    int*    off    = part + 128;                       // NN+1
    int*    csr    = off + NN + 1;                     // NEP

    float* out = (float*)d_out;

    // ---- CSR build (deterministic radix partition) ----
    part_hist<<<NBLK, 256, 0, stream>>>(ei, hist);
    scan_p1<<<HSCAN_BLOCKS, 256, 0, stream>>>(hist, part, HISTN);
    scan_p2<<<1, 128, 0, stream>>>(part, HSCAN_BLOCKS, off);
    scan_p3<<<HSCAN_BLOCKS, 256, 0, stream>>>(hist, part, HISTN);
    part_scatter<<<NBLK, 256, 0, stream>>>(ei, hist, ebuf);
    bucket_csr<<<NBUCK2, 256, 0, stream>>>(hist, ebuf, off, csr);

    // ---- node features (fp16, pca+bio+pad fused) ----
    bio_kernel<<<(NN + 255) / 256, 256, 0, stream>>>(
        x_bio, x_pca, bioW1, biob1, bn0_g, bn0_b, bn0_m, bn0_v, bioW2, biob2, xh);

    // ---- all weight conversions ----
    wconvert_all<<<138, 256, 0, stream>>>(
        Wl1, Wr1, bl1, br1, Wl2, Wr2, bl2, br2, predW, predb,
        wcat1, bcat1, wcat2, bcat2, wpred, bpred);

    // ---- layer-1 transform ----
    mfma_gemm<3, 256, false><<<768, 256, 0, stream>>>(xh, wcat1, bcat1, xcat1, NN, 0, NT64);

    // ---- fused layer-1 edge phase ----
    fused_gat1<<<(NN + 3) / 4, 256, 0, stream>>>(
        off, csr, xcat1, att1, bias1, bn1_g, bn1_b, bn1_m, bn1_v, h1h);

    // ---- layer-2 transform ----
    mfma_gemm<4, 64, false><<<768, 256, 0, stream>>>(h1h, wcat2, bcat2, xcat2, NN, 0, NT64);

    // ---- fused layer-2 edge phase ----
    fused_gat2<<<(NN + 3) / 4, 256, 0, stream>>>(
        off, csr, xcat2, att2, bias2, bn2_g, bn2_b, bn2_m, bn2_v, h2h);

    // ---- prediction head (MFMA, fp32 out) ----
    mfma_gemm<1, 64, true><<<768, 256, 0, stream>>>(h2h, wpred, bpred, out, NN, 50, NT64);
}